// Round 5
// baseline (334.495 us; speedup 1.0000x reference)
//
#include <hip/hip_runtime.h>

#define N 1024
#define THREADS 256
#define EPT 4  // elements per thread per vector (N / THREADS), fallback path

// ---------------------------------------------------------------------------
// Shared pass pipeline (fallback path only, known correct).
// ---------------------------------------------------------------------------
__device__ __forceinline__ float2* run_pipeline(
    float2* bufA, float2* bufB, int tid,
    const float* __restrict__ logits,
    const float* __restrict__ diags,
    const float* __restrict__ subd,
    const float* __restrict__ supd)
{
    float2* src = bufA;
    float2* dst = bufB;

    for (int d = 0; d < 2; ++d) {
        for (int j = 0; j < 9; ++j) {
            const int s = 4 << j;
            const int h = s >> 1;
            const float* lg = logits + (d * 9 + j) * 3;
            const float p0 = 1.0f / (1.0f + expf(-lg[0]));
            const float p1 = 1.0f / (1.0f + expf(-lg[1]));
            const float p2 = 1.0f / (1.0f + expf(-lg[2]));
#pragma unroll
            for (int e = 0; e < EPT; ++e) {
                const int idx = tid + e * THREADS;
                const int base = idx & ~(s - 1);
                const int t = idx & (s - 1);
                const bool lo = (t < h);

                const int eo_t = lo ? (2 * t) : (2 * (t - h) + 1);
                const float2 xt  = src[idx];
                const float2 xeo = src[base + eo_t];
                float2 yt;
                yt.x = xt.x + p0 * (xeo.x - xt.x);
                yt.y = xt.y + p0 * (xeo.y - xt.y);

                const int tm = lo ? (h - 1 - t) : (s + h - 1 - t);
                const float psel = lo ? p1 : p2;
                const int eo_m = (tm < h) ? (2 * tm) : (2 * (tm - h) + 1);
                const float2 xm   = src[base + tm];
                const float2 xmeo = src[base + eo_m];
                float2 ym;
                ym.x = xm.x + p0 * (xmeo.x - xm.x);
                ym.y = xm.y + p0 * (xmeo.y - xm.y);

                float2 o;
                o.x = yt.x + psel * (ym.x - yt.x);
                o.y = yt.y + psel * (ym.y - yt.y);
                dst[idx] = o;
            }
            __syncthreads();
            float2* tmp = src; src = dst; dst = tmp;
        }
        for (int i = 0; i < 10; ++i) {
            const int k = N >> (i + 1);
            const float2* Dg = (const float2*)(diags + (size_t)((d * 10 + i) * N) * 2);
            const float2* Sb = (const float2*)(subd  + (size_t)((d * 10 + i) * N) * 2);
            const float2* Sp = (const float2*)(supd  + (size_t)((d * 10 + i) * N) * 2);
#pragma unroll
            for (int e = 0; e < EPT; ++e) {
                const int idx = tid + e * THREADS;
                const float2 xv = src[idx];
                const float2 dg = Dg[idx];
                float2 o;
                o.x = dg.x * xv.x - dg.y * xv.y;
                o.y = dg.x * xv.y + dg.y * xv.x;
                if (idx >= k) {
                    const float2 xs = src[idx - k];
                    const float2 sb = Sb[idx - k];
                    o.x += sb.x * xs.x - sb.y * xs.y;
                    o.y += sb.x * xs.y + sb.y * xs.x;
                }
                if (idx < N - k) {
                    const float2 xp = src[idx + k];
                    const float2 sp = Sp[idx];
                    o.x += sp.x * xp.x - sp.y * xp.y;
                    o.y += sp.x * xp.y + sp.y * xp.x;
                }
                dst[idx] = o;
            }
            __syncthreads();
            float2* tmp = src; src = dst; dst = tmp;
        }
    }
    return src;
}

// ---------------------------------------------------------------------------
// Fallback: direct per-row kernel (round-1, known correct).
// ---------------------------------------------------------------------------
__global__ __launch_bounds__(THREADS) void trifat_kernel(
    const float* __restrict__ x,
    const float* __restrict__ logits,
    const float* __restrict__ diags,
    const float* __restrict__ subd,
    const float* __restrict__ supd,
    const float* __restrict__ bias,
    float* __restrict__ out,
    int B)
{
    __shared__ float2 bufA[N];
    __shared__ float2 bufB[N];

    const int row = blockIdx.x;
    const int tid = threadIdx.x;
    if (row >= B) return;

    const float* xr = x + (size_t)row * N;
#pragma unroll
    for (int e = 0; e < EPT; ++e) {
        int idx = tid + e * THREADS;
        bufA[idx] = make_float2(xr[idx], 0.0f);
    }
    __syncthreads();

    float2* res = run_pipeline(bufA, bufB, tid, logits, diags, subd, supd);

    float* orow = out + (size_t)row * N;
#pragma unroll
    for (int e = 0; e < EPT; ++e) {
        int idx = tid + e * THREADS;
        orow[idx] = res[idx].x + bias[idx];
    }
}

// ---------------------------------------------------------------------------
// Stage 1: W[j][n] = Re(pipeline(e_j))[n].
// ONE WAVE per block, one basis vector per block: __syncthreads() in a
// 1-wave block retires immediately (no cross-wave drain). Latency hidden by
// 16-way ILP per lane (16 independent tasks per pass). 16 KB LDS.
// ---------------------------------------------------------------------------
__global__ __launch_bounds__(64, 1) void build_W(
    const float* __restrict__ logits,
    const float* __restrict__ diags,
    const float* __restrict__ subd,
    const float* __restrict__ supd,
    float* __restrict__ W)
{
    __shared__ float2 buf[2][N];  // ping-pong, 16 KB

    const int j = blockIdx.x;
    const int tid = threadIdx.x;

#pragma unroll
    for (int e = 0; e < 16; ++e) {
        const int idx = tid + e * 64;
        buf[0][idx] = make_float2(idx == j ? 1.0f : 0.0f, 0.0f);
    }
    __syncthreads();

    int sb = 0;
    for (int d = 0; d < 2; ++d) {
        // ---- 9 perm passes, mirror-pair formulation (512 pair-tasks) ----
        for (int jp = 0; jp < 9; ++jp) {
            const int s = 4 << jp;
            const int h = s >> 1;
            const int hh = s >> 2;
            const float* lg = logits + (d * 9 + jp) * 3;
            const float p0 = 1.0f / (1.0f + expf(-lg[0]));
            const float p1 = 1.0f / (1.0f + expf(-lg[1]));
            const float p2 = 1.0f / (1.0f + expf(-lg[2]));
            const float2* src = buf[sb];
            float2* dst = buf[sb ^ 1];
#pragma unroll
            for (int e = 0; e < 8; ++e) {
                const int pid = tid + e * 64;          // 0..511
                const int w = pid & ((s >> 1) - 1);    // pair within s-block
                const int base = (pid >> (jp + 1)) << (jp + 2);

                int t, tm;
                float psel;
                if (w < hh) { t = w;          tm = h - 1 - w;  psel = p1; }
                else        { const int u = w - hh; t = h + u; tm = s - 1 - u; psel = p2; }

                const int eot = (t  < h) ? (2 * t)  : (2 * (t  - h) + 1);
                const int eom = (tm < h) ? (2 * tm) : (2 * (tm - h) + 1);

                const float2 xt = src[base + t],  xet = src[base + eot];
                const float2 xm = src[base + tm], xem = src[base + eom];
                float2 yt, ym;
                yt.x = xt.x + p0 * (xet.x - xt.x);
                yt.y = xt.y + p0 * (xet.y - xt.y);
                ym.x = xm.x + p0 * (xem.x - xm.x);
                ym.y = xm.y + p0 * (xem.y - xm.y);

                float2 ot, om;
                ot.x = yt.x + psel * (ym.x - yt.x);
                ot.y = yt.y + psel * (ym.y - yt.y);
                om.x = ym.x + psel * (yt.x - ym.x);
                om.y = ym.y + psel * (yt.y - ym.y);
                dst[base + t]  = ot;
                dst[base + tm] = om;
            }
            __syncthreads();
            sb ^= 1;
        }
        // ---- 10 butterfly passes ----
        for (int i = 0; i < 10; ++i) {
            const int k = N >> (i + 1);
            const float2* Dg  = (const float2*)(diags + (size_t)((d * 10 + i) * N) * 2);
            const float2* Sbc = (const float2*)(subd  + (size_t)((d * 10 + i) * N) * 2);
            const float2* Spc = (const float2*)(supd  + (size_t)((d * 10 + i) * N) * 2);
            const float2* src = buf[sb];
            float2* dst = buf[sb ^ 1];
#pragma unroll
            for (int e = 0; e < 16; ++e) {
                const int idx = tid + e * 64;
                const float2 dg = Dg[idx];
                const float2 xv = src[idx];
                float2 o;
                o.x = dg.x * xv.x - dg.y * xv.y;
                o.y = dg.x * xv.y + dg.y * xv.x;
                if (idx >= k) {
                    const float2 sbv = Sbc[idx - k];
                    const float2 xs  = src[idx - k];
                    o.x += sbv.x * xs.x - sbv.y * xs.y;
                    o.y += sbv.x * xs.y + sbv.y * xs.x;
                }
                if (idx < N - k) {
                    const float2 spv = Spc[idx];
                    const float2 xp  = src[idx + k];
                    o.x += spv.x * xp.x - spv.y * xp.y;
                    o.y += spv.x * xp.y + spv.y * xp.x;
                }
                dst[idx] = o;
            }
            __syncthreads();
            sb ^= 1;
        }
    }

#pragma unroll
    for (int e = 0; e < 16; ++e) {
        const int idx = tid + e * 64;
        W[(size_t)j * N + idx] = buf[sb][idx].x;
    }
}

// ---------------------------------------------------------------------------
// bf16 helpers
// ---------------------------------------------------------------------------
__device__ __forceinline__ unsigned short f2bf_rne(float f) {
    unsigned int u = __float_as_uint(f);
    unsigned int r = u + 0x7fffu + ((u >> 16) & 1u);
    return (unsigned short)(r >> 16);
}

// ---------------------------------------------------------------------------
// Stage 2a: transpose W -> Bt [1024][1024] bf16:  Bt[n][j] = bf16(W[j][n])
// ---------------------------------------------------------------------------
__global__ __launch_bounds__(THREADS) void transpose_split(
    const float* __restrict__ W, unsigned short* __restrict__ Bt)
{
    __shared__ float tile[64][65];
    const int j0 = blockIdx.x * 64;
    const int n0 = blockIdx.y * 64;
    const int t = threadIdx.x;
    const int c = t & 63;
    const int rb = t >> 6;  // 0..3

#pragma unroll
    for (int rr = 0; rr < 16; ++rr) {
        const int r = rr * 4 + rb;
        tile[r][c] = W[(size_t)(j0 + r) * N + n0 + c];
    }
    __syncthreads();
#pragma unroll
    for (int rr = 0; rr < 16; ++rr) {
        const int r = rr * 4 + rb;       // output row n0+r
        const float v = tile[c][r];      // = W[j0+c][n0+r]
        Bt[(size_t)(n0 + r) * N + j0 + c] = f2bf_rne(v);
    }
}

// ---------------------------------------------------------------------------
// Stage 2b: x -> A2 [B][1024] bf16 (4 elems/thread, vectorized)
// ---------------------------------------------------------------------------
__global__ __launch_bounds__(THREADS) void conv_x(
    const float* __restrict__ x, unsigned short* __restrict__ A2)
{
    const int gid = blockIdx.x * THREADS + threadIdx.x;
    const float4 v = *(const float4*)(x + (size_t)gid * 4);
    ushort4 o;
    o.x = f2bf_rne(v.x);
    o.y = f2bf_rne(v.y);
    o.z = f2bf_rne(v.z);
    o.w = f2bf_rne(v.w);
    *(ushort4*)(A2 + (size_t)gid * 4) = o;
}

// ---------------------------------------------------------------------------
// Stage 3: 128x128 GEMM, K=1024 (16 iters of BK=64), LDS double-buffered
// global_load_lds staging with XOR swizzle, single barrier per iter.
// ---------------------------------------------------------------------------
typedef __attribute__((ext_vector_type(8))) __bf16 bf16x8;
typedef __attribute__((ext_vector_type(4))) float f32x4;

#define GLB(p) ((const __attribute__((address_space(1))) void*)(p))
#define LDS(p) ((__attribute__((address_space(3))) void*)(p))

__global__ __launch_bounds__(THREADS) void gemm_bf16(
    const unsigned short* __restrict__ A2,  // [B][1024] bf16
    const unsigned short* __restrict__ Bt,  // [1024][1024] bf16
    const float* __restrict__ bias,
    float* __restrict__ out)
{
    __shared__ __align__(16) unsigned short As[2][128 * 64];
    __shared__ __align__(16) unsigned short Bs[2][128 * 64];

    const int m0 = blockIdx.x * 128;
    const int n0 = blockIdx.y * 128;
    const int tid = threadIdx.x;
    const int wave = tid >> 6, lane = tid & 63;
    const int wm = (wave >> 1) * 64, wn = (wave & 1) * 64;
    const int lrow = lane & 15, q = lane >> 4;
    const int r7 = lrow & 7;

    f32x4 acc[4][4] = {};

    auto issue = [&](int kt, int bsel) {
        const int k0 = kt * 64;
        const unsigned short* gA = A2 + (size_t)m0 * N + k0;
        const unsigned short* gB = Bt + (size_t)n0 * N + k0;
#pragma unroll
        for (int r = 0; r < 4; ++r) {
            const int s = r * 256 + tid;
            const int row = s >> 3;
            const int gl = (s & 7) ^ (row & 7);  // XOR-swizzled k-group
            __builtin_amdgcn_global_load_lds(GLB(gA + (size_t)row * N + gl * 8),
                                             LDS(&As[bsel][s * 8]), 16, 0, 0);
            __builtin_amdgcn_global_load_lds(GLB(gB + (size_t)row * N + gl * 8),
                                             LDS(&Bs[bsel][s * 8]), 16, 0, 0);
        }
    };

    issue(0, 0);
    __syncthreads();  // tile 0 ready

    for (int kt = 0; kt < 16; ++kt) {
        const int cur = kt & 1;
        if (kt + 1 < 16) issue(kt + 1, cur ^ 1);  // DMA overlaps compute below

#pragma unroll
        for (int kk = 0; kk < 64; kk += 32) {
            const int pg = ((kk >> 3) + q) ^ r7;  // physical (swizzled) group
            bf16x8 a[4], b[4];
#pragma unroll
            for (int mi = 0; mi < 4; ++mi)
                a[mi] = *(const bf16x8*)(&As[cur][(wm + mi * 16 + lrow) * 64 + pg * 8]);
#pragma unroll
            for (int ni = 0; ni < 4; ++ni)
                b[ni] = *(const bf16x8*)(&Bs[cur][(wn + ni * 16 + lrow) * 64 + pg * 8]);
#pragma unroll
            for (int mi = 0; mi < 4; ++mi)
#pragma unroll
                for (int ni = 0; ni < 4; ++ni)
                    acc[mi][ni] = __builtin_amdgcn_mfma_f32_16x16x32_bf16(
                        a[mi], b[ni], acc[mi][ni], 0, 0, 0);
        }
        __syncthreads();  // drains prefetch DMA + protects buffer reuse
    }

    // epilogue: C/D layout col=lane&15, row=q*4+reg
#pragma unroll
    for (int ni = 0; ni < 4; ++ni) {
        const int col = n0 + wn + ni * 16 + lrow;
        const float bv = bias[col];
#pragma unroll
        for (int mi = 0; mi < 4; ++mi)
#pragma unroll
            for (int r = 0; r < 4; ++r) {
                const int row = m0 + wm + mi * 16 + q * 4 + r;
                out[(size_t)row * N + col] = acc[mi][ni][r] + bv;
            }
    }
}

// ---------------------------------------------------------------------------
extern "C" void kernel_launch(void* const* d_in, const int* in_sizes, int n_in,
                              void* d_out, int out_size, void* d_ws, size_t ws_size,
                              hipStream_t stream) {
    const float* x      = (const float*)d_in[0];
    const float* logits = (const float*)d_in[1];
    const float* diags  = (const float*)d_in[2];
    const float* subd   = (const float*)d_in[3];
    const float* supd   = (const float*)d_in[4];
    const float* bias   = (const float*)d_in[5];
    float* out = (float*)d_out;

    const int B = in_sizes[0] / N;  // 4096

    const size_t off_W  = 0;
    const size_t off_Bt = 4u * 1024 * 1024;                 // W:  1024*1024*4 B
    const size_t off_A2 = off_Bt + 2u * 1024 * 1024;        // Bt: 1024*1024*2 B
    const size_t need   = off_A2 + (size_t)B * N * 2;       // A2: B*1024*2 B

    if (ws_size >= need && (B % 128) == 0) {
        float* W           = (float*)((char*)d_ws + off_W);
        unsigned short* Bt = (unsigned short*)((char*)d_ws + off_Bt);
        unsigned short* A2 = (unsigned short*)((char*)d_ws + off_A2);

        conv_x<<<dim3(B * N / (THREADS * 4)), dim3(THREADS), 0, stream>>>(x, A2);
        build_W<<<dim3(N), dim3(64), 0, stream>>>(logits, diags, subd, supd, W);
        transpose_split<<<dim3(16, 16), dim3(THREADS), 0, stream>>>(W, Bt);
        gemm_bf16<<<dim3(B / 128, 8), dim3(THREADS), 0, stream>>>(A2, Bt, bias, out);
    } else {
        trifat_kernel<<<dim3(B), dim3(THREADS), 0, stream>>>(
            x, logits, diags, subd, supd, bias, out, B);
    }
}

// Round 6
// 145.823 us; speedup vs baseline: 2.2938x; 2.2938x over previous
//
#include <hip/hip_runtime.h>

#define N 1024
#define THREADS 256
#define EPT 4  // elements per thread per vector (N / THREADS), fallback path

// ---------------------------------------------------------------------------
// Shared pass pipeline (fallback path only, known correct).
// ---------------------------------------------------------------------------
__device__ __forceinline__ float2* run_pipeline(
    float2* bufA, float2* bufB, int tid,
    const float* __restrict__ logits,
    const float* __restrict__ diags,
    const float* __restrict__ subd,
    const float* __restrict__ supd)
{
    float2* src = bufA;
    float2* dst = bufB;

    for (int d = 0; d < 2; ++d) {
        for (int j = 0; j < 9; ++j) {
            const int s = 4 << j;
            const int h = s >> 1;
            const float* lg = logits + (d * 9 + j) * 3;
            const float p0 = 1.0f / (1.0f + expf(-lg[0]));
            const float p1 = 1.0f / (1.0f + expf(-lg[1]));
            const float p2 = 1.0f / (1.0f + expf(-lg[2]));
#pragma unroll
            for (int e = 0; e < EPT; ++e) {
                const int idx = tid + e * THREADS;
                const int base = idx & ~(s - 1);
                const int t = idx & (s - 1);
                const bool lo = (t < h);

                const int eo_t = lo ? (2 * t) : (2 * (t - h) + 1);
                const float2 xt  = src[idx];
                const float2 xeo = src[base + eo_t];
                float2 yt;
                yt.x = xt.x + p0 * (xeo.x - xt.x);
                yt.y = xt.y + p0 * (xeo.y - xt.y);

                const int tm = lo ? (h - 1 - t) : (s + h - 1 - t);
                const float psel = lo ? p1 : p2;
                const int eo_m = (tm < h) ? (2 * tm) : (2 * (tm - h) + 1);
                const float2 xm   = src[base + tm];
                const float2 xmeo = src[base + eo_m];
                float2 ym;
                ym.x = xm.x + p0 * (xmeo.x - xm.x);
                ym.y = xm.y + p0 * (xmeo.y - xm.y);

                float2 o;
                o.x = yt.x + psel * (ym.x - yt.x);
                o.y = yt.y + psel * (ym.y - yt.y);
                dst[idx] = o;
            }
            __syncthreads();
            float2* tmp = src; src = dst; dst = tmp;
        }
        for (int i = 0; i < 10; ++i) {
            const int k = N >> (i + 1);
            const float2* Dg = (const float2*)(diags + (size_t)((d * 10 + i) * N) * 2);
            const float2* Sb = (const float2*)(subd  + (size_t)((d * 10 + i) * N) * 2);
            const float2* Sp = (const float2*)(supd  + (size_t)((d * 10 + i) * N) * 2);
#pragma unroll
            for (int e = 0; e < EPT; ++e) {
                const int idx = tid + e * THREADS;
                const float2 xv = src[idx];
                const float2 dg = Dg[idx];
                float2 o;
                o.x = dg.x * xv.x - dg.y * xv.y;
                o.y = dg.x * xv.y + dg.y * xv.x;
                if (idx >= k) {
                    const float2 xs = src[idx - k];
                    const float2 sb = Sb[idx - k];
                    o.x += sb.x * xs.x - sb.y * xs.y;
                    o.y += sb.x * xs.y + sb.y * xs.x;
                }
                if (idx < N - k) {
                    const float2 xp = src[idx + k];
                    const float2 sp = Sp[idx];
                    o.x += sp.x * xp.x - sp.y * xp.y;
                    o.y += sp.x * xp.y + sp.y * xp.x;
                }
                dst[idx] = o;
            }
            __syncthreads();
            float2* tmp = src; src = dst; dst = tmp;
        }
    }
    return src;
}

// ---------------------------------------------------------------------------
// Fallback: direct per-row kernel (round-1, known correct).
// ---------------------------------------------------------------------------
__global__ __launch_bounds__(THREADS) void trifat_kernel(
    const float* __restrict__ x,
    const float* __restrict__ logits,
    const float* __restrict__ diags,
    const float* __restrict__ subd,
    const float* __restrict__ supd,
    const float* __restrict__ bias,
    float* __restrict__ out,
    int B)
{
    __shared__ float2 bufA[N];
    __shared__ float2 bufB[N];

    const int row = blockIdx.x;
    const int tid = threadIdx.x;
    if (row >= B) return;

    const float* xr = x + (size_t)row * N;
#pragma unroll
    for (int e = 0; e < EPT; ++e) {
        int idx = tid + e * THREADS;
        bufA[idx] = make_float2(xr[idx], 0.0f);
    }
    __syncthreads();

    float2* res = run_pipeline(bufA, bufB, tid, logits, diags, subd, supd);

    float* orow = out + (size_t)row * N;
#pragma unroll
    for (int e = 0; e < EPT; ++e) {
        int idx = tid + e * THREADS;
        orow[idx] = res[idx].x + bias[idx];
    }
}

// ---------------------------------------------------------------------------
// Stage 1: W[j][n] = Re(pipeline(e_j))[n].
// Round-4 structure (V=2 vectors/block, 32KB LDS, shared coefficients,
// mirror-pair perms) but 512 threads/block: grid 512 -> 2 blocks/CU ->
// 16 waves/CU (~50% occupancy) for latency hiding (round-4 had only 8).
// ---------------------------------------------------------------------------
#define TBW 512  // build_W threads

__global__ __launch_bounds__(TBW) void build_W(
    const float* __restrict__ logits,
    const float* __restrict__ diags,
    const float* __restrict__ subd,
    const float* __restrict__ supd,
    float* __restrict__ W)
{
    __shared__ float2 buf[2][2][N];  // [buffer][vector][pos], 32 KB

    const int j0 = blockIdx.x * 2;
    const int tid = threadIdx.x;

#pragma unroll
    for (int v = 0; v < 2; ++v)
#pragma unroll
        for (int e = 0; e < 2; ++e) {
            const int idx = tid + e * TBW;
            buf[0][v][idx] = make_float2(idx == (j0 + v) ? 1.0f : 0.0f, 0.0f);
        }
    __syncthreads();

    int sb = 0;
    for (int d = 0; d < 2; ++d) {
        // ---- 9 perm passes, mirror-pair formulation (1024 pair-tasks) ----
        for (int jp = 0; jp < 9; ++jp) {
            const int s = 4 << jp;
            const int h = s >> 1;
            const int hh = s >> 2;
            const float* lg = logits + (d * 9 + jp) * 3;
            const float p0 = 1.0f / (1.0f + expf(-lg[0]));
            const float p1 = 1.0f / (1.0f + expf(-lg[1]));
            const float p2 = 1.0f / (1.0f + expf(-lg[2]));
#pragma unroll
            for (int e = 0; e < 2; ++e) {
                const int tau = tid + e * TBW;         // 0..1023
                const int v = tau >> 9;
                const int pid = tau & 511;             // pair id within vector
                const int w = pid & ((s >> 1) - 1);    // pair within s-block
                const int base = (pid >> (jp + 1)) << (jp + 2);

                int t, tm;
                float psel;
                if (w < hh) { t = w;          tm = h - 1 - w;  psel = p1; }
                else        { const int u = w - hh; t = h + u; tm = s - 1 - u; psel = p2; }

                const int eot = (t  < h) ? (2 * t)  : (2 * (t  - h) + 1);
                const int eom = (tm < h) ? (2 * tm) : (2 * (tm - h) + 1);

                const float2* src = buf[sb][v];
                float2* dst = buf[sb ^ 1][v];

                const float2 xt = src[base + t],  xet = src[base + eot];
                const float2 xm = src[base + tm], xem = src[base + eom];
                float2 yt, ym;
                yt.x = xt.x + p0 * (xet.x - xt.x);
                yt.y = xt.y + p0 * (xet.y - xt.y);
                ym.x = xm.x + p0 * (xem.x - xm.x);
                ym.y = xm.y + p0 * (xem.y - xm.y);

                float2 ot, om;
                ot.x = yt.x + psel * (ym.x - yt.x);
                ot.y = yt.y + psel * (ym.y - yt.y);
                om.x = ym.x + psel * (yt.x - ym.x);
                om.y = ym.y + psel * (yt.y - ym.y);
                dst[base + t]  = ot;
                dst[base + tm] = om;
            }
            __syncthreads();
            sb ^= 1;
        }
        // ---- 10 butterfly passes, coefficients shared across both vectors ----
        for (int i = 0; i < 10; ++i) {
            const int k = N >> (i + 1);
            const float2* Dg  = (const float2*)(diags + (size_t)((d * 10 + i) * N) * 2);
            const float2* Sbc = (const float2*)(subd  + (size_t)((d * 10 + i) * N) * 2);
            const float2* Spc = (const float2*)(supd  + (size_t)((d * 10 + i) * N) * 2);
#pragma unroll
            for (int e = 0; e < 2; ++e) {
                const int idx = tid + e * TBW;
                const float2 dg = Dg[idx];
                float2 sbv = make_float2(0.f, 0.f), spv = make_float2(0.f, 0.f);
                if (idx >= k)     sbv = Sbc[idx - k];
                if (idx < N - k)  spv = Spc[idx];
#pragma unroll
                for (int v = 0; v < 2; ++v) {
                    const float2* src = buf[sb][v];
                    const float2 xv = src[idx];
                    float2 o;
                    o.x = dg.x * xv.x - dg.y * xv.y;
                    o.y = dg.x * xv.y + dg.y * xv.x;
                    if (idx >= k) {
                        const float2 xs = src[idx - k];
                        o.x += sbv.x * xs.x - sbv.y * xs.y;
                        o.y += sbv.x * xs.y + sbv.y * xs.x;
                    }
                    if (idx < N - k) {
                        const float2 xp = src[idx + k];
                        o.x += spv.x * xp.x - spv.y * xp.y;
                        o.y += spv.x * xp.y + spv.y * xp.x;
                    }
                    buf[sb ^ 1][v][idx] = o;
                }
            }
            __syncthreads();
            sb ^= 1;
        }
    }

#pragma unroll
    for (int v = 0; v < 2; ++v)
#pragma unroll
        for (int e = 0; e < 2; ++e) {
            const int idx = tid + e * TBW;
            W[(size_t)(j0 + v) * N + idx] = buf[sb][v][idx].x;
        }
}

// ---------------------------------------------------------------------------
// bf16 helpers
// ---------------------------------------------------------------------------
__device__ __forceinline__ unsigned short f2bf_rne(float f) {
    unsigned int u = __float_as_uint(f);
    unsigned int r = u + 0x7fffu + ((u >> 16) & 1u);
    return (unsigned short)(r >> 16);
}

// ---------------------------------------------------------------------------
// Stage 2a: transpose W -> Bt [1024][1024] bf16:  Bt[n][j] = bf16(W[j][n])
// ---------------------------------------------------------------------------
__global__ __launch_bounds__(THREADS) void transpose_split(
    const float* __restrict__ W, unsigned short* __restrict__ Bt)
{
    __shared__ float tile[64][65];
    const int j0 = blockIdx.x * 64;
    const int n0 = blockIdx.y * 64;
    const int t = threadIdx.x;
    const int c = t & 63;
    const int rb = t >> 6;  // 0..3

#pragma unroll
    for (int rr = 0; rr < 16; ++rr) {
        const int r = rr * 4 + rb;
        tile[r][c] = W[(size_t)(j0 + r) * N + n0 + c];
    }
    __syncthreads();
#pragma unroll
    for (int rr = 0; rr < 16; ++rr) {
        const int r = rr * 4 + rb;       // output row n0+r
        const float v = tile[c][r];      // = W[j0+c][n0+r]
        Bt[(size_t)(n0 + r) * N + j0 + c] = f2bf_rne(v);
    }
}

// ---------------------------------------------------------------------------
// Stage 2b: x -> A2 [B][1024] bf16 (4 elems/thread, vectorized)
// ---------------------------------------------------------------------------
__global__ __launch_bounds__(THREADS) void conv_x(
    const float* __restrict__ x, unsigned short* __restrict__ A2)
{
    const int gid = blockIdx.x * THREADS + threadIdx.x;
    const float4 v = *(const float4*)(x + (size_t)gid * 4);
    ushort4 o;
    o.x = f2bf_rne(v.x);
    o.y = f2bf_rne(v.y);
    o.z = f2bf_rne(v.z);
    o.w = f2bf_rne(v.w);
    *(ushort4*)(A2 + (size_t)gid * 4) = o;
}

// ---------------------------------------------------------------------------
// Stage 3: 128x128 GEMM, K=1024 (16 iters of BK=64), LDS double-buffered
// global_load_lds staging with XOR swizzle, single barrier per iter.
// ---------------------------------------------------------------------------
typedef __attribute__((ext_vector_type(8))) __bf16 bf16x8;
typedef __attribute__((ext_vector_type(4))) float f32x4;

#define GLB(p) ((const __attribute__((address_space(1))) void*)(p))
#define LDS(p) ((__attribute__((address_space(3))) void*)(p))

__global__ __launch_bounds__(THREADS) void gemm_bf16(
    const unsigned short* __restrict__ A2,  // [B][1024] bf16
    const unsigned short* __restrict__ Bt,  // [1024][1024] bf16
    const float* __restrict__ bias,
    float* __restrict__ out)
{
    __shared__ __align__(16) unsigned short As[2][128 * 64];
    __shared__ __align__(16) unsigned short Bs[2][128 * 64];

    const int m0 = blockIdx.x * 128;
    const int n0 = blockIdx.y * 128;
    const int tid = threadIdx.x;
    const int wave = tid >> 6, lane = tid & 63;
    const int wm = (wave >> 1) * 64, wn = (wave & 1) * 64;
    const int lrow = lane & 15, q = lane >> 4;
    const int r7 = lrow & 7;

    f32x4 acc[4][4] = {};

    auto issue = [&](int kt, int bsel) {
        const int k0 = kt * 64;
        const unsigned short* gA = A2 + (size_t)m0 * N + k0;
        const unsigned short* gB = Bt + (size_t)n0 * N + k0;
#pragma unroll
        for (int r = 0; r < 4; ++r) {
            const int s = r * 256 + tid;
            const int row = s >> 3;
            const int gl = (s & 7) ^ (row & 7);  // XOR-swizzled k-group
            __builtin_amdgcn_global_load_lds(GLB(gA + (size_t)row * N + gl * 8),
                                             LDS(&As[bsel][s * 8]), 16, 0, 0);
            __builtin_amdgcn_global_load_lds(GLB(gB + (size_t)row * N + gl * 8),
                                             LDS(&Bs[bsel][s * 8]), 16, 0, 0);
        }
    };

    issue(0, 0);
    __syncthreads();  // tile 0 ready

    for (int kt = 0; kt < 16; ++kt) {
        const int cur = kt & 1;
        if (kt + 1 < 16) issue(kt + 1, cur ^ 1);  // DMA overlaps compute below

#pragma unroll
        for (int kk = 0; kk < 64; kk += 32) {
            const int pg = ((kk >> 3) + q) ^ r7;  // physical (swizzled) group
            bf16x8 a[4], b[4];
#pragma unroll
            for (int mi = 0; mi < 4; ++mi)
                a[mi] = *(const bf16x8*)(&As[cur][(wm + mi * 16 + lrow) * 64 + pg * 8]);
#pragma unroll
            for (int ni = 0; ni < 4; ++ni)
                b[ni] = *(const bf16x8*)(&Bs[cur][(wn + ni * 16 + lrow) * 64 + pg * 8]);
#pragma unroll
            for (int mi = 0; mi < 4; ++mi)
#pragma unroll
                for (int ni = 0; ni < 4; ++ni)
                    acc[mi][ni] = __builtin_amdgcn_mfma_f32_16x16x32_bf16(
                        a[mi], b[ni], acc[mi][ni], 0, 0, 0);
        }
        __syncthreads();  // drains prefetch DMA + protects buffer reuse
    }

    // epilogue: C/D layout col=lane&15, row=q*4+reg
#pragma unroll
    for (int ni = 0; ni < 4; ++ni) {
        const int col = n0 + wn + ni * 16 + lrow;
        const float bv = bias[col];
#pragma unroll
        for (int mi = 0; mi < 4; ++mi)
#pragma unroll
            for (int r = 0; r < 4; ++r) {
                const int row = m0 + wm + mi * 16 + q * 4 + r;
                out[(size_t)row * N + col] = acc[mi][ni][r] + bv;
            }
    }
}

// ---------------------------------------------------------------------------
extern "C" void kernel_launch(void* const* d_in, const int* in_sizes, int n_in,
                              void* d_out, int out_size, void* d_ws, size_t ws_size,
                              hipStream_t stream) {
    const float* x      = (const float*)d_in[0];
    const float* logits = (const float*)d_in[1];
    const float* diags  = (const float*)d_in[2];
    const float* subd   = (const float*)d_in[3];
    const float* supd   = (const float*)d_in[4];
    const float* bias   = (const float*)d_in[5];
    float* out = (float*)d_out;

    const int B = in_sizes[0] / N;  // 4096

    const size_t off_W  = 0;
    const size_t off_Bt = 4u * 1024 * 1024;                 // W:  1024*1024*4 B
    const size_t off_A2 = off_Bt + 2u * 1024 * 1024;        // Bt: 1024*1024*2 B
    const size_t need   = off_A2 + (size_t)B * N * 2;       // A2: B*1024*2 B

    if (ws_size >= need && (B % 128) == 0) {
        float* W           = (float*)((char*)d_ws + off_W);
        unsigned short* Bt = (unsigned short*)((char*)d_ws + off_Bt);
        unsigned short* A2 = (unsigned short*)((char*)d_ws + off_A2);

        conv_x<<<dim3(B * N / (THREADS * 4)), dim3(THREADS), 0, stream>>>(x, A2);
        build_W<<<dim3(N / 2), dim3(TBW), 0, stream>>>(logits, diags, subd, supd, W);
        transpose_split<<<dim3(16, 16), dim3(THREADS), 0, stream>>>(W, Bt);
        gemm_bf16<<<dim3(B / 128, 8), dim3(THREADS), 0, stream>>>(A2, Bt, bias, out);
    } else {
        trifat_kernel<<<dim3(B), dim3(THREADS), 0, stream>>>(
            x, logits, diags, subd, supd, bias, out, B);
    }
}

// Round 7
// 140.511 us; speedup vs baseline: 2.3806x; 1.0378x over previous
//
#include <hip/hip_runtime.h>

#define N 1024
#define THREADS 256
#define EPT 4  // fallback path

// ---------------------------------------------------------------------------
// Shared pass pipeline (fallback path only, known correct).
// ---------------------------------------------------------------------------
__device__ __forceinline__ float2* run_pipeline(
    float2* bufA, float2* bufB, int tid,
    const float* __restrict__ logits,
    const float* __restrict__ diags,
    const float* __restrict__ subd,
    const float* __restrict__ supd)
{
    float2* src = bufA;
    float2* dst = bufB;

    for (int d = 0; d < 2; ++d) {
        for (int j = 0; j < 9; ++j) {
            const int s = 4 << j;
            const int h = s >> 1;
            const float* lg = logits + (d * 9 + j) * 3;
            const float p0 = 1.0f / (1.0f + expf(-lg[0]));
            const float p1 = 1.0f / (1.0f + expf(-lg[1]));
            const float p2 = 1.0f / (1.0f + expf(-lg[2]));
#pragma unroll
            for (int e = 0; e < EPT; ++e) {
                const int idx = tid + e * THREADS;
                const int base = idx & ~(s - 1);
                const int t = idx & (s - 1);
                const bool lo = (t < h);

                const int eo_t = lo ? (2 * t) : (2 * (t - h) + 1);
                const float2 xt  = src[idx];
                const float2 xeo = src[base + eo_t];
                float2 yt;
                yt.x = xt.x + p0 * (xeo.x - xt.x);
                yt.y = xt.y + p0 * (xeo.y - xt.y);

                const int tm = lo ? (h - 1 - t) : (s + h - 1 - t);
                const float psel = lo ? p1 : p2;
                const int eo_m = (tm < h) ? (2 * tm) : (2 * (tm - h) + 1);
                const float2 xm   = src[base + tm];
                const float2 xmeo = src[base + eo_m];
                float2 ym;
                ym.x = xm.x + p0 * (xmeo.x - xm.x);
                ym.y = xm.y + p0 * (xmeo.y - xm.y);

                float2 o;
                o.x = yt.x + psel * (ym.x - yt.x);
                o.y = yt.y + psel * (ym.y - yt.y);
                dst[idx] = o;
            }
            __syncthreads();
            float2* tmp = src; src = dst; dst = tmp;
        }
        for (int i = 0; i < 10; ++i) {
            const int k = N >> (i + 1);
            const float2* Dg = (const float2*)(diags + (size_t)((d * 10 + i) * N) * 2);
            const float2* Sb = (const float2*)(subd  + (size_t)((d * 10 + i) * N) * 2);
            const float2* Sp = (const float2*)(supd  + (size_t)((d * 10 + i) * N) * 2);
#pragma unroll
            for (int e = 0; e < EPT; ++e) {
                const int idx = tid + e * THREADS;
                const float2 xv = src[idx];
                const float2 dg = Dg[idx];
                float2 o;
                o.x = dg.x * xv.x - dg.y * xv.y;
                o.y = dg.x * xv.y + dg.y * xv.x;
                if (idx >= k) {
                    const float2 xs = src[idx - k];
                    const float2 sb = Sb[idx - k];
                    o.x += sb.x * xs.x - sb.y * xs.y;
                    o.y += sb.x * xs.y + sb.y * xs.x;
                }
                if (idx < N - k) {
                    const float2 xp = src[idx + k];
                    const float2 sp = Sp[idx];
                    o.x += sp.x * xp.x - sp.y * xp.y;
                    o.y += sp.x * xp.y + sp.y * xp.x;
                }
                dst[idx] = o;
            }
            __syncthreads();
            float2* tmp = src; src = dst; dst = tmp;
        }
    }
    return src;
}

// ---------------------------------------------------------------------------
// Fallback: direct per-row kernel (round-1, known correct).
// ---------------------------------------------------------------------------
__global__ __launch_bounds__(THREADS) void trifat_kernel(
    const float* __restrict__ x,
    const float* __restrict__ logits,
    const float* __restrict__ diags,
    const float* __restrict__ subd,
    const float* __restrict__ supd,
    const float* __restrict__ bias,
    float* __restrict__ out,
    int B)
{
    __shared__ float2 bufA[N];
    __shared__ float2 bufB[N];

    const int row = blockIdx.x;
    const int tid = threadIdx.x;
    if (row >= B) return;

    const float* xr = x + (size_t)row * N;
#pragma unroll
    for (int e = 0; e < EPT; ++e) {
        int idx = tid + e * THREADS;
        bufA[idx] = make_float2(xr[idx], 0.0f);
    }
    __syncthreads();

    float2* res = run_pipeline(bufA, bufB, tid, logits, diags, subd, supd);

    float* orow = out + (size_t)row * N;
#pragma unroll
    for (int e = 0; e < EPT; ++e) {
        int idx = tid + e * THREADS;
        orow[idx] = res[idx].x + bias[idx];
    }
}

// ---------------------------------------------------------------------------
// bf16 helper
// ---------------------------------------------------------------------------
__device__ __forceinline__ unsigned short f2bf_rne(float f) {
    unsigned int u = __float_as_uint(f);
    unsigned int r = u + 0x7fffu + ((u >> 16) & 1u);
    return (unsigned short)(r >> 16);
}

// ---------------------------------------------------------------------------
// Fused prep kernel, grid = 768 x 512 threads:
//  blocks [0,512):   build_W body (round-6, V=2 vectors/block, 32 KB LDS,
//                    16 waves/CU) -> epilogue scatter-writes Bt[n][j] bf16
//                    directly (no W buffer, no transpose kernel).
//  blocks [512,768): conv_x: x fp32 -> A2 bf16, 16384 elems/block.
// Branch is block-uniform, so the build path's barriers are legal.
// ---------------------------------------------------------------------------
#define TBW 512
#define NB_BUILD 512

__global__ __launch_bounds__(TBW) void prep_kernel(
    const float* __restrict__ logits,
    const float* __restrict__ diags,
    const float* __restrict__ subd,
    const float* __restrict__ supd,
    const float* __restrict__ x,
    unsigned short* __restrict__ Bt,   // [1024][1024] bf16, Bt[n][j]
    unsigned short* __restrict__ A2)   // [B][1024] bf16
{
    __shared__ float2 buf[2][2][N];  // [buffer][vector][pos], 32 KB

    const int tid = threadIdx.x;

    if (blockIdx.x >= NB_BUILD) {
        // ---------------- conv role ----------------
        const int cb = blockIdx.x - NB_BUILD;        // 0..255
        const size_t base4 = (size_t)cb * 4096;      // float4 index base
#pragma unroll
        for (int r = 0; r < 8; ++r) {
            const size_t g4 = base4 + r * 512 + tid;
            const float4 v = *(const float4*)(x + g4 * 4);
            ushort4 o;
            o.x = f2bf_rne(v.x);
            o.y = f2bf_rne(v.y);
            o.z = f2bf_rne(v.z);
            o.w = f2bf_rne(v.w);
            *(ushort4*)(A2 + g4 * 4) = o;
        }
        return;
    }

    // ---------------- build role (round-6 body, unchanged) ----------------
    const int j0 = blockIdx.x * 2;

#pragma unroll
    for (int v = 0; v < 2; ++v)
#pragma unroll
        for (int e = 0; e < 2; ++e) {
            const int idx = tid + e * TBW;
            buf[0][v][idx] = make_float2(idx == (j0 + v) ? 1.0f : 0.0f, 0.0f);
        }
    __syncthreads();

    int sb = 0;
    for (int d = 0; d < 2; ++d) {
        // ---- 9 perm passes, mirror-pair formulation ----
        for (int jp = 0; jp < 9; ++jp) {
            const int s = 4 << jp;
            const int h = s >> 1;
            const int hh = s >> 2;
            const float* lg = logits + (d * 9 + jp) * 3;
            const float p0 = 1.0f / (1.0f + expf(-lg[0]));
            const float p1 = 1.0f / (1.0f + expf(-lg[1]));
            const float p2 = 1.0f / (1.0f + expf(-lg[2]));
#pragma unroll
            for (int e = 0; e < 2; ++e) {
                const int tau = tid + e * TBW;         // 0..1023
                const int v = tau >> 9;
                const int pid = tau & 511;             // pair id within vector
                const int w = pid & ((s >> 1) - 1);    // pair within s-block
                const int base = (pid >> (jp + 1)) << (jp + 2);

                int t, tm;
                float psel;
                if (w < hh) { t = w;          tm = h - 1 - w;  psel = p1; }
                else        { const int u = w - hh; t = h + u; tm = s - 1 - u; psel = p2; }

                const int eot = (t  < h) ? (2 * t)  : (2 * (t  - h) + 1);
                const int eom = (tm < h) ? (2 * tm) : (2 * (tm - h) + 1);

                const float2* src = buf[sb][v];
                float2* dst = buf[sb ^ 1][v];

                const float2 xt = src[base + t],  xet = src[base + eot];
                const float2 xm = src[base + tm], xem = src[base + eom];
                float2 yt, ym;
                yt.x = xt.x + p0 * (xet.x - xt.x);
                yt.y = xt.y + p0 * (xet.y - xt.y);
                ym.x = xm.x + p0 * (xem.x - xm.x);
                ym.y = xm.y + p0 * (xem.y - xm.y);

                float2 ot, om;
                ot.x = yt.x + psel * (ym.x - yt.x);
                ot.y = yt.y + psel * (ym.y - yt.y);
                om.x = ym.x + psel * (yt.x - ym.x);
                om.y = ym.y + psel * (yt.y - ym.y);
                dst[base + t]  = ot;
                dst[base + tm] = om;
            }
            __syncthreads();
            sb ^= 1;
        }
        // ---- 10 butterfly passes, coefficients shared across both vectors ----
        for (int i = 0; i < 10; ++i) {
            const int k = N >> (i + 1);
            const float2* Dg  = (const float2*)(diags + (size_t)((d * 10 + i) * N) * 2);
            const float2* Sbc = (const float2*)(subd  + (size_t)((d * 10 + i) * N) * 2);
            const float2* Spc = (const float2*)(supd  + (size_t)((d * 10 + i) * N) * 2);
#pragma unroll
            for (int e = 0; e < 2; ++e) {
                const int idx = tid + e * TBW;
                const float2 dg = Dg[idx];
                float2 sbv = make_float2(0.f, 0.f), spv = make_float2(0.f, 0.f);
                if (idx >= k)     sbv = Sbc[idx - k];
                if (idx < N - k)  spv = Spc[idx];
#pragma unroll
                for (int v = 0; v < 2; ++v) {
                    const float2* src = buf[sb][v];
                    const float2 xv = src[idx];
                    float2 o;
                    o.x = dg.x * xv.x - dg.y * xv.y;
                    o.y = dg.x * xv.y + dg.y * xv.x;
                    if (idx >= k) {
                        const float2 xs = src[idx - k];
                        o.x += sbv.x * xs.x - sbv.y * xs.y;
                        o.y += sbv.x * xs.y + sbv.y * xs.x;
                    }
                    if (idx < N - k) {
                        const float2 xp = src[idx + k];
                        o.x += spv.x * xp.x - spv.y * xp.y;
                        o.y += spv.x * xp.y + spv.y * xp.x;
                    }
                    buf[sb ^ 1][v][idx] = o;
                }
            }
            __syncthreads();
            sb ^= 1;
        }
    }

    // ---- epilogue: scatter-write transposed bf16 directly: Bt[n][j0+v] ----
#pragma unroll
    for (int v = 0; v < 2; ++v)
#pragma unroll
        for (int e = 0; e < 2; ++e) {
            const int idx = tid + e * TBW;
            Bt[(size_t)idx * N + (j0 + v)] = f2bf_rne(buf[sb][v][idx].x);
        }
}

// ---------------------------------------------------------------------------
// GEMM: 128x128 tile, K=1024 (16 iters of BK=64), LDS double-buffered
// global_load_lds staging with XOR swizzle, single barrier per iter.
// (unchanged from round 6)
// ---------------------------------------------------------------------------
typedef __attribute__((ext_vector_type(8))) __bf16 bf16x8;
typedef __attribute__((ext_vector_type(4))) float f32x4;

#define GLB(p) ((const __attribute__((address_space(1))) void*)(p))
#define LDS(p) ((__attribute__((address_space(3))) void*)(p))

__global__ __launch_bounds__(THREADS) void gemm_bf16(
    const unsigned short* __restrict__ A2,  // [B][1024] bf16
    const unsigned short* __restrict__ Bt,  // [1024][1024] bf16
    const float* __restrict__ bias,
    float* __restrict__ out)
{
    __shared__ __align__(16) unsigned short As[2][128 * 64];
    __shared__ __align__(16) unsigned short Bs[2][128 * 64];

    const int m0 = blockIdx.x * 128;
    const int n0 = blockIdx.y * 128;
    const int tid = threadIdx.x;
    const int wave = tid >> 6, lane = tid & 63;
    const int wm = (wave >> 1) * 64, wn = (wave & 1) * 64;
    const int lrow = lane & 15, q = lane >> 4;
    const int r7 = lrow & 7;

    f32x4 acc[4][4] = {};

    auto issue = [&](int kt, int bsel) {
        const int k0 = kt * 64;
        const unsigned short* gA = A2 + (size_t)m0 * N + k0;
        const unsigned short* gB = Bt + (size_t)n0 * N + k0;
#pragma unroll
        for (int r = 0; r < 4; ++r) {
            const int s = r * 256 + tid;
            const int row = s >> 3;
            const int gl = (s & 7) ^ (row & 7);  // XOR-swizzled k-group
            __builtin_amdgcn_global_load_lds(GLB(gA + (size_t)row * N + gl * 8),
                                             LDS(&As[bsel][s * 8]), 16, 0, 0);
            __builtin_amdgcn_global_load_lds(GLB(gB + (size_t)row * N + gl * 8),
                                             LDS(&Bs[bsel][s * 8]), 16, 0, 0);
        }
    };

    issue(0, 0);
    __syncthreads();  // tile 0 ready

    for (int kt = 0; kt < 16; ++kt) {
        const int cur = kt & 1;
        if (kt + 1 < 16) issue(kt + 1, cur ^ 1);  // DMA overlaps compute below

#pragma unroll
        for (int kk = 0; kk < 64; kk += 32) {
            const int pg = ((kk >> 3) + q) ^ r7;  // physical (swizzled) group
            bf16x8 a[4], b[4];
#pragma unroll
            for (int mi = 0; mi < 4; ++mi)
                a[mi] = *(const bf16x8*)(&As[cur][(wm + mi * 16 + lrow) * 64 + pg * 8]);
#pragma unroll
            for (int ni = 0; ni < 4; ++ni)
                b[ni] = *(const bf16x8*)(&Bs[cur][(wn + ni * 16 + lrow) * 64 + pg * 8]);
#pragma unroll
            for (int mi = 0; mi < 4; ++mi)
#pragma unroll
                for (int ni = 0; ni < 4; ++ni)
                    acc[mi][ni] = __builtin_amdgcn_mfma_f32_16x16x32_bf16(
                        a[mi], b[ni], acc[mi][ni], 0, 0, 0);
        }
        __syncthreads();  // drains prefetch DMA + protects buffer reuse
    }

    // epilogue: C/D layout col=lane&15, row=q*4+reg
#pragma unroll
    for (int ni = 0; ni < 4; ++ni) {
        const int col = n0 + wn + ni * 16 + lrow;
        const float bv = bias[col];
#pragma unroll
        for (int mi = 0; mi < 4; ++mi)
#pragma unroll
            for (int r = 0; r < 4; ++r) {
                const int row = m0 + wm + mi * 16 + q * 4 + r;
                out[(size_t)row * N + col] = acc[mi][ni][r] + bv;
            }
    }
}

// ---------------------------------------------------------------------------
extern "C" void kernel_launch(void* const* d_in, const int* in_sizes, int n_in,
                              void* d_out, int out_size, void* d_ws, size_t ws_size,
                              hipStream_t stream) {
    const float* x      = (const float*)d_in[0];
    const float* logits = (const float*)d_in[1];
    const float* diags  = (const float*)d_in[2];
    const float* subd   = (const float*)d_in[3];
    const float* supd   = (const float*)d_in[4];
    const float* bias   = (const float*)d_in[5];
    float* out = (float*)d_out;

    const int B = in_sizes[0] / N;  // 4096

    const size_t off_Bt = 0;                                // Bt: 1024*1024*2 B
    const size_t off_A2 = 2u * 1024 * 1024;
    const size_t need   = off_A2 + (size_t)B * N * 2;       // A2: B*1024*2 B

    if (ws_size >= need && B == 4096) {
        unsigned short* Bt = (unsigned short*)((char*)d_ws + off_Bt);
        unsigned short* A2 = (unsigned short*)((char*)d_ws + off_A2);

        prep_kernel<<<dim3(NB_BUILD + 256), dim3(TBW), 0, stream>>>(
            logits, diags, subd, supd, x, Bt, A2);
        gemm_bf16<<<dim3(B / 128, 8), dim3(THREADS), 0, stream>>>(A2, Bt, bias, out);
    } else {
        trifat_kernel<<<dim3(B), dim3(THREADS), 0, stream>>>(
            x, logits, diags, subd, supd, bias, out, B);
    }
}

// Round 8
// 134.780 us; speedup vs baseline: 2.4818x; 1.0425x over previous
//
#include <hip/hip_runtime.h>

#define N 1024
#define THREADS 256
#define EPT 4  // fallback path

// ---------------------------------------------------------------------------
// Shared pass pipeline (fallback path only, known correct).
// ---------------------------------------------------------------------------
__device__ __forceinline__ float2* run_pipeline(
    float2* bufA, float2* bufB, int tid,
    const float* __restrict__ logits,
    const float* __restrict__ diags,
    const float* __restrict__ subd,
    const float* __restrict__ supd)
{
    float2* src = bufA;
    float2* dst = bufB;

    for (int d = 0; d < 2; ++d) {
        for (int j = 0; j < 9; ++j) {
            const int s = 4 << j;
            const int h = s >> 1;
            const float* lg = logits + (d * 9 + j) * 3;
            const float p0 = 1.0f / (1.0f + expf(-lg[0]));
            const float p1 = 1.0f / (1.0f + expf(-lg[1]));
            const float p2 = 1.0f / (1.0f + expf(-lg[2]));
#pragma unroll
            for (int e = 0; e < EPT; ++e) {
                const int idx = tid + e * THREADS;
                const int base = idx & ~(s - 1);
                const int t = idx & (s - 1);
                const bool lo = (t < h);

                const int eo_t = lo ? (2 * t) : (2 * (t - h) + 1);
                const float2 xt  = src[idx];
                const float2 xeo = src[base + eo_t];
                float2 yt;
                yt.x = xt.x + p0 * (xeo.x - xt.x);
                yt.y = xt.y + p0 * (xeo.y - xt.y);

                const int tm = lo ? (h - 1 - t) : (s + h - 1 - t);
                const float psel = lo ? p1 : p2;
                const int eo_m = (tm < h) ? (2 * tm) : (2 * (tm - h) + 1);
                const float2 xm   = src[base + tm];
                const float2 xmeo = src[base + eo_m];
                float2 ym;
                ym.x = xm.x + p0 * (xmeo.x - xm.x);
                ym.y = xm.y + p0 * (xmeo.y - xm.y);

                float2 o;
                o.x = yt.x + psel * (ym.x - yt.x);
                o.y = yt.y + psel * (ym.y - yt.y);
                dst[idx] = o;
            }
            __syncthreads();
            float2* tmp = src; src = dst; dst = tmp;
        }
        for (int i = 0; i < 10; ++i) {
            const int k = N >> (i + 1);
            const float2* Dg = (const float2*)(diags + (size_t)((d * 10 + i) * N) * 2);
            const float2* Sb = (const float2*)(subd  + (size_t)((d * 10 + i) * N) * 2);
            const float2* Sp = (const float2*)(supd  + (size_t)((d * 10 + i) * N) * 2);
#pragma unroll
            for (int e = 0; e < EPT; ++e) {
                const int idx = tid + e * THREADS;
                const float2 xv = src[idx];
                const float2 dg = Dg[idx];
                float2 o;
                o.x = dg.x * xv.x - dg.y * xv.y;
                o.y = dg.x * xv.y + dg.y * xv.x;
                if (idx >= k) {
                    const float2 xs = src[idx - k];
                    const float2 sb = Sb[idx - k];
                    o.x += sb.x * xs.x - sb.y * xs.y;
                    o.y += sb.x * xs.y + sb.y * xs.x;
                }
                if (idx < N - k) {
                    const float2 xp = src[idx + k];
                    const float2 sp = Sp[idx];
                    o.x += sp.x * xp.x - sp.y * xp.y;
                    o.y += sp.x * xp.y + sp.y * xp.x;
                }
                dst[idx] = o;
            }
            __syncthreads();
            float2* tmp = src; src = dst; dst = tmp;
        }
    }
    return src;
}

// ---------------------------------------------------------------------------
// Fallback: direct per-row kernel (round-1, known correct).
// ---------------------------------------------------------------------------
__global__ __launch_bounds__(THREADS) void trifat_kernel(
    const float* __restrict__ x,
    const float* __restrict__ logits,
    const float* __restrict__ diags,
    const float* __restrict__ subd,
    const float* __restrict__ supd,
    const float* __restrict__ bias,
    float* __restrict__ out,
    int B)
{
    __shared__ float2 bufA[N];
    __shared__ float2 bufB[N];

    const int row = blockIdx.x;
    const int tid = threadIdx.x;
    if (row >= B) return;

    const float* xr = x + (size_t)row * N;
#pragma unroll
    for (int e = 0; e < EPT; ++e) {
        int idx = tid + e * THREADS;
        bufA[idx] = make_float2(xr[idx], 0.0f);
    }
    __syncthreads();

    float2* res = run_pipeline(bufA, bufB, tid, logits, diags, subd, supd);

    float* orow = out + (size_t)row * N;
#pragma unroll
    for (int e = 0; e < EPT; ++e) {
        int idx = tid + e * THREADS;
        orow[idx] = res[idx].x + bias[idx];
    }
}

// ---------------------------------------------------------------------------
// bf16 helper
// ---------------------------------------------------------------------------
__device__ __forceinline__ unsigned short f2bf_rne(float f) {
    unsigned int u = __float_as_uint(f);
    unsigned int r = u + 0x7fffu + ((u >> 16) & 1u);
    return (unsigned short)(r >> 16);
}

// ---------------------------------------------------------------------------
// Fused prep kernel (unchanged from round 7, known 56 µs):
//  blocks [0,512):   build two basis-vector images, scatter-write Bt bf16
//  blocks [512,768): conv x -> A2 bf16
// ---------------------------------------------------------------------------
#define TBW 512
#define NB_BUILD 512

__global__ __launch_bounds__(TBW) void prep_kernel(
    const float* __restrict__ logits,
    const float* __restrict__ diags,
    const float* __restrict__ subd,
    const float* __restrict__ supd,
    const float* __restrict__ x,
    unsigned short* __restrict__ Bt,   // [1024][1024] bf16, Bt[n][j]
    unsigned short* __restrict__ A2)   // [B][1024] bf16
{
    __shared__ float2 buf[2][2][N];  // [buffer][vector][pos], 32 KB

    const int tid = threadIdx.x;

    if (blockIdx.x >= NB_BUILD) {
        // ---------------- conv role ----------------
        const int cb = blockIdx.x - NB_BUILD;        // 0..255
        const size_t base4 = (size_t)cb * 4096;      // float4 index base
#pragma unroll
        for (int r = 0; r < 8; ++r) {
            const size_t g4 = base4 + r * 512 + tid;
            const float4 v = *(const float4*)(x + g4 * 4);
            ushort4 o;
            o.x = f2bf_rne(v.x);
            o.y = f2bf_rne(v.y);
            o.z = f2bf_rne(v.z);
            o.w = f2bf_rne(v.w);
            *(ushort4*)(A2 + g4 * 4) = o;
        }
        return;
    }

    // ---------------- build role ----------------
    const int j0 = blockIdx.x * 2;

#pragma unroll
    for (int v = 0; v < 2; ++v)
#pragma unroll
        for (int e = 0; e < 2; ++e) {
            const int idx = tid + e * TBW;
            buf[0][v][idx] = make_float2(idx == (j0 + v) ? 1.0f : 0.0f, 0.0f);
        }
    __syncthreads();

    int sb = 0;
    for (int d = 0; d < 2; ++d) {
        // ---- 9 perm passes, mirror-pair formulation ----
        for (int jp = 0; jp < 9; ++jp) {
            const int s = 4 << jp;
            const int h = s >> 1;
            const int hh = s >> 2;
            const float* lg = logits + (d * 9 + jp) * 3;
            const float p0 = 1.0f / (1.0f + expf(-lg[0]));
            const float p1 = 1.0f / (1.0f + expf(-lg[1]));
            const float p2 = 1.0f / (1.0f + expf(-lg[2]));
#pragma unroll
            for (int e = 0; e < 2; ++e) {
                const int tau = tid + e * TBW;         // 0..1023
                const int v = tau >> 9;
                const int pid = tau & 511;             // pair id within vector
                const int w = pid & ((s >> 1) - 1);    // pair within s-block
                const int base = (pid >> (jp + 1)) << (jp + 2);

                int t, tm;
                float psel;
                if (w < hh) { t = w;          tm = h - 1 - w;  psel = p1; }
                else        { const int u = w - hh; t = h + u; tm = s - 1 - u; psel = p2; }

                const int eot = (t  < h) ? (2 * t)  : (2 * (t  - h) + 1);
                const int eom = (tm < h) ? (2 * tm) : (2 * (tm - h) + 1);

                const float2* src = buf[sb][v];
                float2* dst = buf[sb ^ 1][v];

                const float2 xt = src[base + t],  xet = src[base + eot];
                const float2 xm = src[base + tm], xem = src[base + eom];
                float2 yt, ym;
                yt.x = xt.x + p0 * (xet.x - xt.x);
                yt.y = xt.y + p0 * (xet.y - xt.y);
                ym.x = xm.x + p0 * (xem.x - xm.x);
                ym.y = xm.y + p0 * (xem.y - xm.y);

                float2 ot, om;
                ot.x = yt.x + psel * (ym.x - yt.x);
                ot.y = yt.y + psel * (ym.y - yt.y);
                om.x = ym.x + psel * (yt.x - ym.x);
                om.y = ym.y + psel * (yt.y - ym.y);
                dst[base + t]  = ot;
                dst[base + tm] = om;
            }
            __syncthreads();
            sb ^= 1;
        }
        // ---- 10 butterfly passes, coefficients shared across both vectors ----
        for (int i = 0; i < 10; ++i) {
            const int k = N >> (i + 1);
            const float2* Dg  = (const float2*)(diags + (size_t)((d * 10 + i) * N) * 2);
            const float2* Sbc = (const float2*)(subd  + (size_t)((d * 10 + i) * N) * 2);
            const float2* Spc = (const float2*)(supd  + (size_t)((d * 10 + i) * N) * 2);
#pragma unroll
            for (int e = 0; e < 2; ++e) {
                const int idx = tid + e * TBW;
                const float2 dg = Dg[idx];
                float2 sbv = make_float2(0.f, 0.f), spv = make_float2(0.f, 0.f);
                if (idx >= k)     sbv = Sbc[idx - k];
                if (idx < N - k)  spv = Spc[idx];
#pragma unroll
                for (int v = 0; v < 2; ++v) {
                    const float2* src = buf[sb][v];
                    const float2 xv = src[idx];
                    float2 o;
                    o.x = dg.x * xv.x - dg.y * xv.y;
                    o.y = dg.x * xv.y + dg.y * xv.x;
                    if (idx >= k) {
                        const float2 xs = src[idx - k];
                        o.x += sbv.x * xs.x - sbv.y * xs.y;
                        o.y += sbv.x * xs.y + sbv.y * xs.x;
                    }
                    if (idx < N - k) {
                        const float2 xp = src[idx + k];
                        o.x += spv.x * xp.x - spv.y * xp.y;
                        o.y += spv.x * xp.y + spv.y * xp.x;
                    }
                    buf[sb ^ 1][v][idx] = o;
                }
            }
            __syncthreads();
            sb ^= 1;
        }
    }

    // ---- epilogue: scatter-write transposed bf16 directly: Bt[n][j0+v] ----
#pragma unroll
    for (int v = 0; v < 2; ++v)
#pragma unroll
        for (int e = 0; e < 2; ++e) {
            const int idx = tid + e * TBW;
            Bt[(size_t)idx * N + (j0 + v)] = f2bf_rne(buf[sb][v][idx].x);
        }
}

// ---------------------------------------------------------------------------
// GEMM: BM=64 x BN=128 tile, BK=64, grid (64,8)=512 blocks -> 2 blocks/CU.
// m97-style 2-barrier single-buffer K-loop (no explicit double-buffer: the
// compiler's conservative vmcnt(0) before ds_read defeats dbuf; inter-block
// overlap at 2 blocks/CU hides the drain instead). XOR-swizzled LDS.
// 4 waves, each 32(m) x 64(n) = 2x4 frags of 16x16x32.
// ---------------------------------------------------------------------------
typedef __attribute__((ext_vector_type(8))) __bf16 bf16x8;
typedef __attribute__((ext_vector_type(4))) float f32x4;

#define GLB(p) ((const __attribute__((address_space(1))) void*)(p))
#define LDS(p) ((__attribute__((address_space(3))) void*)(p))

__global__ __launch_bounds__(THREADS) void gemm_bf16(
    const unsigned short* __restrict__ A2,  // [B][1024] bf16
    const unsigned short* __restrict__ Bt,  // [1024][1024] bf16
    const float* __restrict__ bias,
    float* __restrict__ out)
{
    __shared__ __align__(16) unsigned short As[64 * 64];    // 8 KB
    __shared__ __align__(16) unsigned short Bs[128 * 64];   // 16 KB

    const int m0 = blockIdx.x * 64;
    const int n0 = blockIdx.y * 128;
    const int tid = threadIdx.x;
    const int wave = tid >> 6, lane = tid & 63;
    const int wm = (wave >> 1) * 32, wn = (wave & 1) * 64;
    const int lrow = lane & 15, q = lane >> 4;
    const int r7 = lrow & 7;

    f32x4 acc[2][4] = {};

    for (int kt = 0; kt < 16; ++kt) {
        const int k0 = kt * 64;
        __syncthreads();  // previous tile fully consumed
        {
            const unsigned short* gA = A2 + (size_t)m0 * N + k0;
            const unsigned short* gB = Bt + (size_t)n0 * N + k0;
            // A: 512 slots (2/thread)
#pragma unroll
            for (int r = 0; r < 2; ++r) {
                const int s = r * 256 + tid;
                const int row = s >> 3;
                const int gl = (s & 7) ^ (row & 7);
                __builtin_amdgcn_global_load_lds(GLB(gA + (size_t)row * N + gl * 8),
                                                 LDS(As + s * 8), 16, 0, 0);
            }
            // B: 1024 slots (4/thread)
#pragma unroll
            for (int r = 0; r < 4; ++r) {
                const int s = r * 256 + tid;
                const int row = s >> 3;
                const int gl = (s & 7) ^ (row & 7);
                __builtin_amdgcn_global_load_lds(GLB(gB + (size_t)row * N + gl * 8),
                                                 LDS(Bs + s * 8), 16, 0, 0);
            }
        }
        __syncthreads();  // DMA drained -> tile ready

#pragma unroll
        for (int kk = 0; kk < 64; kk += 32) {
            const int pg = ((kk >> 3) + q) ^ r7;  // physical (swizzled) group
            bf16x8 a[2], b[4];
#pragma unroll
            for (int mi = 0; mi < 2; ++mi)
                a[mi] = *(const bf16x8*)(As + (wm + mi * 16 + lrow) * 64 + pg * 8);
#pragma unroll
            for (int ni = 0; ni < 4; ++ni)
                b[ni] = *(const bf16x8*)(Bs + (wn + ni * 16 + lrow) * 64 + pg * 8);
#pragma unroll
            for (int mi = 0; mi < 2; ++mi)
#pragma unroll
                for (int ni = 0; ni < 4; ++ni)
                    acc[mi][ni] = __builtin_amdgcn_mfma_f32_16x16x32_bf16(
                        a[mi], b[ni], acc[mi][ni], 0, 0, 0);
        }
    }

    // epilogue: C/D layout col=lane&15, row=q*4+reg
#pragma unroll
    for (int ni = 0; ni < 4; ++ni) {
        const int col = n0 + wn + ni * 16 + lrow;
        const float bv = bias[col];
#pragma unroll
        for (int mi = 0; mi < 2; ++mi)
#pragma unroll
            for (int r = 0; r < 4; ++r) {
                const int row = m0 + wm + mi * 16 + q * 4 + r;
                out[(size_t)row * N + col] = acc[mi][ni][r] + bv;
            }
    }
}

// ---------------------------------------------------------------------------
extern "C" void kernel_launch(void* const* d_in, const int* in_sizes, int n_in,
                              void* d_out, int out_size, void* d_ws, size_t ws_size,
                              hipStream_t stream) {
    const float* x      = (const float*)d_in[0];
    const float* logits = (const float*)d_in[1];
    const float* diags  = (const float*)d_in[2];
    const float* subd   = (const float*)d_in[3];
    const float* supd   = (const float*)d_in[4];
    const float* bias   = (const float*)d_in[5];
    float* out = (float*)d_out;

    const int B = in_sizes[0] / N;  // 4096

    const size_t off_Bt = 0;                                // Bt: 1024*1024*2 B
    const size_t off_A2 = 2u * 1024 * 1024;
    const size_t need   = off_A2 + (size_t)B * N * 2;       // A2: B*1024*2 B

    if (ws_size >= need && B == 4096) {
        unsigned short* Bt = (unsigned short*)((char*)d_ws + off_Bt);
        unsigned short* A2 = (unsigned short*)((char*)d_ws + off_A2);

        prep_kernel<<<dim3(NB_BUILD + 256), dim3(TBW), 0, stream>>>(
            logits, diags, subd, supd, x, Bt, A2);
        gemm_bf16<<<dim3(B / 64, 8), dim3(THREADS), 0, stream>>>(A2, Bt, bias, out);
    } else {
        trifat_kernel<<<dim3(B), dim3(THREADS), 0, stream>>>(
            x, logits, diags, subd, supd, bias, out, B);
    }
}